// Round 10
// baseline (354.306 us; speedup 1.0000x reference)
//
#include <hip/hip_runtime.h>
#include <hip/hip_bf16.h>

// ============ DIAGNOSTIC ROUND: K1 scan phase repeated x8 ====================
// Identical outputs to the R5 kernel (csr/row_cnt rewritten with the same
// values each rep; scatter runs once). dur_us ~= base + 7*scan_time, and the
// inflated k1 dispatch surfaces in rocprof top-5 with its own counters.
#define SCAN_REP 8

#define NN 8192   // nodes
#define NE 8192   // edges
#define CC 256    // channels
#define CAP 128   // max nnz per row/col (mean ~34, sigma ~5.7)

typedef __attribute__((ext_vector_type(8))) short bf16x8;
typedef __attribute__((ext_vector_type(8))) unsigned short u16x8;
typedef __attribute__((ext_vector_type(4))) float f32x4;

static __device__ __forceinline__ ushort f2b(float f) {       // RNE f32->bf16
    unsigned u = __float_as_uint(f);
    return (ushort)((u + 0x7fffu + ((u >> 16) & 1u)) >> 16);
}
static __device__ __forceinline__ float b2f(ushort u) {
    return __uint_as_float((unsigned)u << 16);
}

// ---- K1: convert x0/W to bf16, scan B rows -> CSR + row_cnt (x SCAN_REP),
//          then scatter -> CSC + edge weighted-degree sums (once).
__global__ __launch_bounds__(256) void k1_scan(const float* __restrict__ B,
                                               const float* __restrict__ x0,
                                               const float* __restrict__ W,
                                               ushort* __restrict__ x0b,
                                               ushort* __restrict__ Wb,
                                               int* __restrict__ csr,
                                               int* __restrict__ row_cnt,
                                               int* __restrict__ col_cnt,
                                               int* __restrict__ csc,
                                               float* __restrict__ edge_wsum) {
    __shared__ int wcnt[4];
    {
        int i = blockIdx.x * 1024 + threadIdx.x * 4;
        float4 v = *(const float4*)(x0 + i);
        ushort4 u; u.x = f2b(v.x); u.y = f2b(v.y); u.z = f2b(v.z); u.w = f2b(v.w);
        *(ushort4*)(x0b + i) = u;
        if (blockIdx.x < 64) {
            float4 w = *(const float4*)(W + i);
            ushort4 uw; uw.x = f2b(w.x); uw.y = f2b(w.y); uw.z = f2b(w.z); uw.w = f2b(w.w);
            *(ushort4*)(Wb + i) = uw;
        }
    }
    const int wave = threadIdx.x >> 6;
    const int lane = threadIdx.x & 63;
    const int row  = blockIdx.x * 4 + wave;
    const float4* rp = (const float4*)(B + (size_t)row * NE);
    int* outp = csr + (size_t)row * CAP;
    int cnt = 0;
    #pragma unroll 1
    for (int rep = 0; rep < SCAN_REP; ++rep) {
        if (lane == 0) wcnt[wave] = 0;      // per-wave counter; same-wave ds ordered
        float4 v = rp[lane];
        #pragma unroll 1
        for (int it = 0; it < 32; ++it) {   // 32 iterations, 1 KB/wave, 2-deep
            float4 vn = v;
            if (it < 31) vn = rp[(it + 1) * 64 + lane];
            float fs = v.x + v.y + v.z + v.w;   // binary entries: #nonzero
            if (__ballot(fs != 0.f)) {
                int m = (int)fs;
                int pos = 0;
                if (m) pos = atomicAdd(&wcnt[wave], m);
                int e0 = (it * 64 + lane) * 4;
                if (v.x != 0.f) { if (pos < CAP) outp[pos] = e0;     ++pos; }
                if (v.y != 0.f) { if (pos < CAP) outp[pos] = e0 + 1; ++pos; }
                if (v.z != 0.f) { if (pos < CAP) outp[pos] = e0 + 2; ++pos; }
                if (v.w != 0.f) { if (pos < CAP) outp[pos] = e0 + 3; ++pos; }
            }
            v = vn;
        }
        cnt = wcnt[wave];                   // read after same-wave atomics
        cnt = cnt < CAP ? cnt : CAP;
    }
    if (lane == 0) row_cnt[row] = cnt;
    const float deg = (float)cnt;
    for (int i = lane; i < cnt; i += 64) {  // scatter: once
        int e = outp[i];
        int pos = atomicAdd(&col_cnt[e], 1);
        if (pos < CAP) csc[(size_t)e * CAP + pos] = row;
        atomicAdd(&edge_wsum[e], deg);      // integer-valued: exact, order-free
    }
}

// ---- K4: m01s[e][:] = rsqrt(edge_deg) * sum_{n in col e} x0b[n][:]
__global__ __launch_bounds__(256) void k4_edge_agg(const ushort* __restrict__ x0b,
                                                   const int* __restrict__ csc,
                                                   const int* __restrict__ col_cnt,
                                                   const float* __restrict__ edge_wsum,
                                                   ushort* __restrict__ m01s) {
    const int wave = threadIdx.x >> 6;
    const int lane = threadIdx.x & 63;
    const int half = lane >> 5;
    const int cl = lane & 31;
    const int e = blockIdx.x * 4 + wave;
    int cnt = col_cnt[e]; if (cnt > CAP) cnt = CAP;
    const float er = rsqrtf(edge_wsum[e] / (float)cnt);
    const int* cp = csc + (size_t)e * CAP;
    const int idx = cp[lane];
    const ushort* xb = x0b + cl * 8;
    float a0[8] = {}, a1[8] = {};
    const int lim = cnt < 64 ? cnt : 64;
    int i = 0;
    for (; i + 8 <= lim; i += 8) {
        int n0 = __shfl(idx, i + half);
        int n1 = __shfl(idx, i + 2 + half);
        int n2 = __shfl(idx, i + 4 + half);
        int n3 = __shfl(idx, i + 6 + half);
        u16x8 r0 = *(const u16x8*)(xb + (size_t)n0 * CC);
        u16x8 r1 = *(const u16x8*)(xb + (size_t)n1 * CC);
        u16x8 r2 = *(const u16x8*)(xb + (size_t)n2 * CC);
        u16x8 r3 = *(const u16x8*)(xb + (size_t)n3 * CC);
        #pragma unroll
        for (int c = 0; c < 8; ++c) {
            a0[c] += b2f(r0[c]); a1[c] += b2f(r1[c]);
            a0[c] += b2f(r2[c]); a1[c] += b2f(r3[c]);
        }
    }
    for (; i + 2 <= lim; i += 2) {
        int n0 = __shfl(idx, i + half);
        u16x8 r0 = *(const u16x8*)(xb + (size_t)n0 * CC);
        #pragma unroll
        for (int c = 0; c < 8; ++c) a0[c] += b2f(r0[c]);
    }
    if (i < lim) {
        int n0 = __shfl(idx, i);                       // shfl before divergence
        if (half == 0) {
            u16x8 r0 = *(const u16x8*)(xb + (size_t)n0 * CC);
            #pragma unroll
            for (int c = 0; c < 8; ++c) a0[c] += b2f(r0[c]);
        }
    }
    if (cnt > 64 && half == 0) {                       // vanishing probability
        for (int j = 64; j < cnt; ++j) {
            int n2 = cp[j];
            u16x8 r0 = *(const u16x8*)(xb + (size_t)n2 * CC);
            #pragma unroll
            for (int c = 0; c < 8; ++c) a0[c] += b2f(r0[c]);
        }
    }
    u16x8 r8;
    #pragma unroll
    for (int c = 0; c < 8; ++c) {
        float t = a0[c] + a1[c];
        t += __shfl_xor(t, 32);
        r8[c] = f2b(t * er);
    }
    if (half == 0) *(u16x8*)(m01s + (size_t)e * CC + cl * 8) = r8;
}

// ---- K5': fused node aggregation + skip + GEMM epilogue ---------------------
__global__ __launch_bounds__(1024, 8) void k5_fused(const ushort* __restrict__ x0b,
                                                    const ushort* __restrict__ m01s,
                                                    const int* __restrict__ csr,
                                                    const int* __restrict__ row_cnt,
                                                    const ushort* __restrict__ Wb,
                                                    float* __restrict__ out) {
    __shared__ __align__(16) ushort xs[16][264];
    const int w = threadIdx.x >> 6;
    const int lane = threadIdx.x & 63;
    const int half = lane >> 5;
    const int cl = lane & 31;
    const int n = blockIdx.x * 16 + w;
    const int cnt = row_cnt[n];
    const float nr = rsqrtf((float)cnt);
    const int* ep = csr + (size_t)n * CAP;
    const int idx = ep[lane];
    const ushort* mb = m01s + cl * 8;
    float a0[8] = {}, a1[8] = {};
    const int lim = cnt < 64 ? cnt : 64;
    int i = 0;
    for (; i + 8 <= lim; i += 8) {
        int e0 = __shfl(idx, i + half);
        int e1 = __shfl(idx, i + 2 + half);
        int e2 = __shfl(idx, i + 4 + half);
        int e3 = __shfl(idx, i + 6 + half);
        u16x8 r0 = *(const u16x8*)(mb + (size_t)e0 * CC);
        u16x8 r1 = *(const u16x8*)(mb + (size_t)e1 * CC);
        u16x8 r2 = *(const u16x8*)(mb + (size_t)e2 * CC);
        u16x8 r3 = *(const u16x8*)(mb + (size_t)e3 * CC);
        #pragma unroll
        for (int c = 0; c < 8; ++c) {
            a0[c] += b2f(r0[c]); a1[c] += b2f(r1[c]);
            a0[c] += b2f(r2[c]); a1[c] += b2f(r3[c]);
        }
    }
    for (; i + 2 <= lim; i += 2) {
        int e0 = __shfl(idx, i + half);
        u16x8 r0 = *(const u16x8*)(mb + (size_t)e0 * CC);
        #pragma unroll
        for (int c = 0; c < 8; ++c) a0[c] += b2f(r0[c]);
    }
    if (i < lim) {
        int e0 = __shfl(idx, i);
        if (half == 0) {
            u16x8 r0 = *(const u16x8*)(mb + (size_t)e0 * CC);
            #pragma unroll
            for (int c = 0; c < 8; ++c) a0[c] += b2f(r0[c]);
        }
    }
    if (cnt > 64 && half == 0) {
        for (int j = 64; j < cnt; ++j) {
            int e2 = ep[j];
            u16x8 r0 = *(const u16x8*)(mb + (size_t)e2 * CC);
            #pragma unroll
            for (int c = 0; c < 8; ++c) a0[c] += b2f(r0[c]);
        }
    }
    u16x8 x = *(const u16x8*)(x0b + (size_t)n * CC + cl * 8);
    const float s = 0.9f * nr;
    u16x8 r8;
    #pragma unroll
    for (int c = 0; c < 8; ++c) {
        float t = a0[c] + a1[c];
        t += __shfl_xor(t, 32);
        r8[c] = f2b(s * t + 0.1f * b2f(x[c]));
    }
    if (half == 0) *(u16x8*)(&xs[w][cl * 8]) = r8;
    __syncthreads();
    const int lr = lane & 15, lk = lane >> 4;
    const int n0 = w * 16;
    f32x4 acc = {0.f, 0.f, 0.f, 0.f};
    #pragma unroll
    for (int kb = 0; kb < 8; ++kb) {
        bf16x8 a = *(const bf16x8*)(&xs[lr][kb * 32 + lk * 8]);
        bf16x8 b = *(const bf16x8*)(Wb + (size_t)(n0 + lr) * CC + kb * 32 + lk * 8);
        acc = __builtin_amdgcn_mfma_f32_16x16x32_bf16(a, b, acc, 0, 0, 0);
    }
    const size_t rb = (size_t)blockIdx.x * 16;
    #pragma unroll
    for (int r = 0; r < 4; ++r) {
        int row = lk * 4 + r;                      // C/D: col=lane&15, row=(lane>>4)*4+reg
        int col = n0 + lr;
        float sk = b2f(xs[row][col]);
        out[(rb + row) * CC + col] = 0.5f * sk + 0.5f * acc[r];
    }
}

// ---- launch -----------------------------------------------------------------
extern "C" void kernel_launch(void* const* d_in, const int* in_sizes, int n_in,
                              void* d_out, int out_size, void* d_ws, size_t ws_size,
                              hipStream_t stream) {
    const float* x0 = (const float*)d_in[0];
    const float* B  = (const float*)d_in[1];
    const float* W  = (const float*)d_in[2];
    float* out = (float*)d_out;

    char* ws = (char*)d_ws;
    const size_t need = (17ull << 20) + 4ull * NE * 4;
    if (ws_size < need) return;

    int*    csr       = (int*)(ws);                    // 4 MB
    int*    csc       = (int*)(ws + (4ull << 20));     // 4 MB
    ushort* m01s      = (ushort*)(ws + (8ull << 20));  // 4 MB (bf16)
    ushort* x0b       = (ushort*)(ws + (12ull << 20)); // 4 MB (bf16)
    ushort* Wb        = (ushort*)(ws + (16ull << 20)); // 128 KB (bf16)
    int*    row_cnt   = (int*)(ws + (16ull << 20) + (256u << 10)); // 32 KB
    int*    col_cnt   = row_cnt + NN;                  // 32 KB (zeroed)
    float*  edge_wsum = (float*)(col_cnt + NE);        // 32 KB (zeroed, adjacent)

    hipMemsetAsync(col_cnt, 0, 2ull * NE * 4, stream);

    k1_scan<<<NN / 4, 256, 0, stream>>>(B, x0, W, x0b, Wb, csr, row_cnt, col_cnt, csc, edge_wsum);
    k4_edge_agg<<<NE / 4, 256, 0, stream>>>(x0b, csc, col_cnt, edge_wsum, m01s);
    k5_fused<<<NN / 16, 1024, 0, stream>>>(x0b, m01s, csr, row_cnt, Wb, out);
}

// Round 11
// 103.115 us; speedup vs baseline: 3.4360x; 3.4360x over previous
//
#include <hip/hip_runtime.h>
#include <hip/hip_bf16.h>

#define NN 8192   // nodes
#define NE 8192   // edges
#define CC 256    // channels
#define CAP 128   // max nnz per row/col (mean ~34, sigma ~5.7)

typedef __attribute__((ext_vector_type(8))) short bf16x8;
typedef __attribute__((ext_vector_type(8))) unsigned short u16x8;
typedef __attribute__((ext_vector_type(4))) float f32x4;

static __device__ __forceinline__ ushort f2b(float f) {       // RNE f32->bf16
    unsigned u = __float_as_uint(f);
    return (ushort)((u + 0x7fffu + ((u >> 16) & 1u)) >> 16);
}
static __device__ __forceinline__ float b2f(ushort u) {
    return __uint_as_float((unsigned)u << 16);
}

// ---- K1: convert x0/W to bf16 (fused prologue), scan B rows -> CSR + row_cnt
// (binary incidence: LDS-atomic slot allocation), then scatter -> CSC + edge
// weighted-degree sums. Measured (R10 diag): scan = 35.8 us at ~7.15 TB/s
// combined L3+HBM = stream ceiling; VALUBusy 15.8% -> nothing VALU-side left.
__global__ __launch_bounds__(256) void k1_scan(const float* __restrict__ B,
                                               const float* __restrict__ x0,
                                               const float* __restrict__ W,
                                               ushort* __restrict__ x0b,
                                               ushort* __restrict__ Wb,
                                               int* __restrict__ csr,
                                               int* __restrict__ row_cnt,
                                               int* __restrict__ col_cnt,
                                               int* __restrict__ csc,
                                               float* __restrict__ edge_wsum) {
    __shared__ int wcnt[4];
    {
        int i = blockIdx.x * 1024 + threadIdx.x * 4;
        float4 v = *(const float4*)(x0 + i);
        ushort4 u; u.x = f2b(v.x); u.y = f2b(v.y); u.z = f2b(v.z); u.w = f2b(v.w);
        *(ushort4*)(x0b + i) = u;
        if (blockIdx.x < 64) {
            float4 w = *(const float4*)(W + i);
            ushort4 uw; uw.x = f2b(w.x); uw.y = f2b(w.y); uw.z = f2b(w.z); uw.w = f2b(w.w);
            *(ushort4*)(Wb + i) = uw;
        }
    }
    const int wave = threadIdx.x >> 6;
    const int lane = threadIdx.x & 63;
    const int row  = blockIdx.x * 4 + wave;
    const float4* rp = (const float4*)(B + (size_t)row * NE);
    int* outp = csr + (size_t)row * CAP;
    if (lane == 0) wcnt[wave] = 0;          // per-wave counter; same-wave ds ordered
    float4 v = rp[lane];
    #pragma unroll 1
    for (int it = 0; it < 32; ++it) {       // 32 iterations, 1 KB/wave, 2-deep
        float4 vn = v;
        if (it < 31) vn = rp[(it + 1) * 64 + lane];
        float fs = v.x + v.y + v.z + v.w;   // binary entries: #nonzero
        if (__ballot(fs != 0.f)) {
            int m = (int)fs;
            int pos = 0;
            if (m) pos = atomicAdd(&wcnt[wave], m);
            int e0 = (it * 64 + lane) * 4;
            if (v.x != 0.f) { if (pos < CAP) outp[pos] = e0;     ++pos; }
            if (v.y != 0.f) { if (pos < CAP) outp[pos] = e0 + 1; ++pos; }
            if (v.z != 0.f) { if (pos < CAP) outp[pos] = e0 + 2; ++pos; }
            if (v.w != 0.f) { if (pos < CAP) outp[pos] = e0 + 3; ++pos; }
        }
        v = vn;
    }
    int cnt = wcnt[wave];                   // read after same-wave atomics
    cnt = cnt < CAP ? cnt : CAP;
    if (lane == 0) row_cnt[row] = cnt;
    const float deg = (float)cnt;
    for (int i = lane; i < cnt; i += 64) {
        int e = outp[i];
        int pos = atomicAdd(&col_cnt[e], 1);
        if (pos < CAP) csc[(size_t)e * CAP + pos] = row;
        atomicAdd(&edge_wsum[e], deg);      // integer-valued: exact, order-free
    }
}

// ---- K4: m01s[e][:] = rsqrt(edge_deg) * sum_{n in col e} x0b[n][:]
// 16 B/lane, half-wave = one 512 B row; ~6.4 TB/s = random-row transaction
// ceiling (R10 analysis; slab/NT/coop all null).
__global__ __launch_bounds__(256) void k4_edge_agg(const ushort* __restrict__ x0b,
                                                   const int* __restrict__ csc,
                                                   const int* __restrict__ col_cnt,
                                                   const float* __restrict__ edge_wsum,
                                                   ushort* __restrict__ m01s) {
    const int wave = threadIdx.x >> 6;
    const int lane = threadIdx.x & 63;
    const int half = lane >> 5;
    const int cl = lane & 31;
    const int e = blockIdx.x * 4 + wave;
    int cnt = col_cnt[e]; if (cnt > CAP) cnt = CAP;
    const float er = rsqrtf(edge_wsum[e] / (float)cnt);
    const int* cp = csc + (size_t)e * CAP;
    const int idx = cp[lane];
    const ushort* xb = x0b + cl * 8;
    float a0[8] = {}, a1[8] = {};
    const int lim = cnt < 64 ? cnt : 64;
    int i = 0;
    for (; i + 8 <= lim; i += 8) {
        int n0 = __shfl(idx, i + half);
        int n1 = __shfl(idx, i + 2 + half);
        int n2 = __shfl(idx, i + 4 + half);
        int n3 = __shfl(idx, i + 6 + half);
        u16x8 r0 = *(const u16x8*)(xb + (size_t)n0 * CC);
        u16x8 r1 = *(const u16x8*)(xb + (size_t)n1 * CC);
        u16x8 r2 = *(const u16x8*)(xb + (size_t)n2 * CC);
        u16x8 r3 = *(const u16x8*)(xb + (size_t)n3 * CC);
        #pragma unroll
        for (int c = 0; c < 8; ++c) {
            a0[c] += b2f(r0[c]); a1[c] += b2f(r1[c]);
            a0[c] += b2f(r2[c]); a1[c] += b2f(r3[c]);
        }
    }
    for (; i + 2 <= lim; i += 2) {
        int n0 = __shfl(idx, i + half);
        u16x8 r0 = *(const u16x8*)(xb + (size_t)n0 * CC);
        #pragma unroll
        for (int c = 0; c < 8; ++c) a0[c] += b2f(r0[c]);
    }
    if (i < lim) {
        int n0 = __shfl(idx, i);                       // shfl before divergence
        if (half == 0) {
            u16x8 r0 = *(const u16x8*)(xb + (size_t)n0 * CC);
            #pragma unroll
            for (int c = 0; c < 8; ++c) a0[c] += b2f(r0[c]);
        }
    }
    if (cnt > 64 && half == 0) {                       // vanishing probability
        for (int j = 64; j < cnt; ++j) {
            int n2 = cp[j];
            u16x8 r0 = *(const u16x8*)(xb + (size_t)n2 * CC);
            #pragma unroll
            for (int c = 0; c < 8; ++c) a0[c] += b2f(r0[c]);
        }
    }
    u16x8 r8;
    #pragma unroll
    for (int c = 0; c < 8; ++c) {
        float t = a0[c] + a1[c];
        t += __shfl_xor(t, 32);
        r8[c] = f2b(t * er);
    }
    if (half == 0) *(u16x8*)(m01s + (size_t)e * CC + cl * 8) = r8;
}

// ---- K5': fused node aggregation + skip + GEMM epilogue.
// out stores are NON-TEMPORAL: zero-reuse 8 MB stream whose only L2 effect
// would be evicting the m01s gather table mid-kernel.
__global__ __launch_bounds__(1024, 8) void k5_fused(const ushort* __restrict__ x0b,
                                                    const ushort* __restrict__ m01s,
                                                    const int* __restrict__ csr,
                                                    const int* __restrict__ row_cnt,
                                                    const ushort* __restrict__ Wb,
                                                    float* __restrict__ out) {
    __shared__ __align__(16) ushort xs[16][264];
    const int w = threadIdx.x >> 6;
    const int lane = threadIdx.x & 63;
    const int half = lane >> 5;
    const int cl = lane & 31;
    const int n = blockIdx.x * 16 + w;
    const int cnt = row_cnt[n];
    const float nr = rsqrtf((float)cnt);
    const int* ep = csr + (size_t)n * CAP;
    const int idx = ep[lane];
    const ushort* mb = m01s + cl * 8;
    float a0[8] = {}, a1[8] = {};
    const int lim = cnt < 64 ? cnt : 64;
    int i = 0;
    for (; i + 8 <= lim; i += 8) {
        int e0 = __shfl(idx, i + half);
        int e1 = __shfl(idx, i + 2 + half);
        int e2 = __shfl(idx, i + 4 + half);
        int e3 = __shfl(idx, i + 6 + half);
        u16x8 r0 = *(const u16x8*)(mb + (size_t)e0 * CC);
        u16x8 r1 = *(const u16x8*)(mb + (size_t)e1 * CC);
        u16x8 r2 = *(const u16x8*)(mb + (size_t)e2 * CC);
        u16x8 r3 = *(const u16x8*)(mb + (size_t)e3 * CC);
        #pragma unroll
        for (int c = 0; c < 8; ++c) {
            a0[c] += b2f(r0[c]); a1[c] += b2f(r1[c]);
            a0[c] += b2f(r2[c]); a1[c] += b2f(r3[c]);
        }
    }
    for (; i + 2 <= lim; i += 2) {
        int e0 = __shfl(idx, i + half);
        u16x8 r0 = *(const u16x8*)(mb + (size_t)e0 * CC);
        #pragma unroll
        for (int c = 0; c < 8; ++c) a0[c] += b2f(r0[c]);
    }
    if (i < lim) {
        int e0 = __shfl(idx, i);
        if (half == 0) {
            u16x8 r0 = *(const u16x8*)(mb + (size_t)e0 * CC);
            #pragma unroll
            for (int c = 0; c < 8; ++c) a0[c] += b2f(r0[c]);
        }
    }
    if (cnt > 64 && half == 0) {
        for (int j = 64; j < cnt; ++j) {
            int e2 = ep[j];
            u16x8 r0 = *(const u16x8*)(mb + (size_t)e2 * CC);
            #pragma unroll
            for (int c = 0; c < 8; ++c) a0[c] += b2f(r0[c]);
        }
    }
    u16x8 x = *(const u16x8*)(x0b + (size_t)n * CC + cl * 8);
    const float s = 0.9f * nr;
    u16x8 r8;
    #pragma unroll
    for (int c = 0; c < 8; ++c) {
        float t = a0[c] + a1[c];
        t += __shfl_xor(t, 32);
        r8[c] = f2b(s * t + 0.1f * b2f(x[c]));
    }
    if (half == 0) *(u16x8*)(&xs[w][cl * 8]) = r8;
    __syncthreads();
    const int lr = lane & 15, lk = lane >> 4;
    const int n0 = w * 16;
    f32x4 acc = {0.f, 0.f, 0.f, 0.f};
    #pragma unroll
    for (int kb = 0; kb < 8; ++kb) {
        bf16x8 a = *(const bf16x8*)(&xs[lr][kb * 32 + lk * 8]);
        bf16x8 b = *(const bf16x8*)(Wb + (size_t)(n0 + lr) * CC + kb * 32 + lk * 8);
        acc = __builtin_amdgcn_mfma_f32_16x16x32_bf16(a, b, acc, 0, 0, 0);
    }
    const size_t rb = (size_t)blockIdx.x * 16;
    #pragma unroll
    for (int r = 0; r < 4; ++r) {
        int row = lk * 4 + r;                      // C/D: col=lane&15, row=(lane>>4)*4+reg
        int col = n0 + lr;
        float sk = b2f(xs[row][col]);
        __builtin_nontemporal_store(0.5f * sk + 0.5f * acc[r],
                                    out + (rb + row) * CC + col);
    }
}

// ---- launch -----------------------------------------------------------------
extern "C" void kernel_launch(void* const* d_in, const int* in_sizes, int n_in,
                              void* d_out, int out_size, void* d_ws, size_t ws_size,
                              hipStream_t stream) {
    const float* x0 = (const float*)d_in[0];
    const float* B  = (const float*)d_in[1];
    const float* W  = (const float*)d_in[2];
    float* out = (float*)d_out;

    char* ws = (char*)d_ws;
    const size_t need = (17ull << 20) + 4ull * NE * 4;
    if (ws_size < need) return;

    int*    csr       = (int*)(ws);                    // 4 MB
    int*    csc       = (int*)(ws + (4ull << 20));     // 4 MB
    ushort* m01s      = (ushort*)(ws + (8ull << 20));  // 4 MB (bf16)
    ushort* x0b       = (ushort*)(ws + (12ull << 20)); // 4 MB (bf16)
    ushort* Wb        = (ushort*)(ws + (16ull << 20)); // 128 KB (bf16)
    int*    row_cnt   = (int*)(ws + (16ull << 20) + (256u << 10)); // 32 KB
    int*    col_cnt   = row_cnt + NN;                  // 32 KB (zeroed)
    float*  edge_wsum = (float*)(col_cnt + NE);        // 32 KB (zeroed, adjacent)

    hipMemsetAsync(col_cnt, 0, 2ull * NE * 4, stream);

    k1_scan<<<NN / 4, 256, 0, stream>>>(B, x0, W, x0b, Wb, csr, row_cnt, col_cnt, csc, edge_wsum);
    k4_edge_agg<<<NE / 4, 256, 0, stream>>>(x0b, csc, col_cnt, edge_wsum, m01s);
    k5_fused<<<NN / 16, 1024, 0, stream>>>(x0b, m01s, csr, row_cnt, Wb, out);
}